// Round 12
// baseline (866.207 us; speedup 1.0000x reference)
//
#include <hip/hip_runtime.h>

#define EPS_BN 1e-5f
#define ROWPAD 8    // CSR rows padded to multiple of 8 edges (src=0,w=0 filler)
#define HSEG 32768  // histogram bins per segment (packed u8 -> 32 KB LDS)
#define HC 64       // histogram edge-chunks
#define MAXB 512    // max dst-buckets (256 nodes each)

typedef unsigned short u16;
typedef unsigned char u8;
typedef int v4i __attribute__((ext_vector_type(4)));

__device__ __forceinline__ float b2f(u16 u) {
  return __uint_as_float(((unsigned)u) << 16);
}
__device__ __forceinline__ u16 f2b(float f) {  // RTNE
  unsigned u = __float_as_uint(f);
  u += 0x7fffu + ((u >> 16) & 1u);
  return (u16)(u >> 16);
}

// ---------------- preprocessing: packed-u8 LDS segmented histograms ----------------
__global__ void k_histseg(const int* __restrict__ src, const int* __restrict__ dst,
                          unsigned* __restrict__ partial, int E, int SP) {
  __shared__ unsigned bins[HSEG / 4];
  int s = blockIdx.x, c = blockIdx.y, z = blockIdx.z;
  int t = threadIdx.x;
  for (int i = t; i < HSEG / 4; i += 256) bins[i] = 0;
  __syncthreads();
  const int* keys = z ? dst : src;
  int lo = s * HSEG;
  int ck = (E + HC - 1) / HC;
  int e0 = c * ck, e1 = e0 + ck; if (e1 > E) e1 = E;
  for (int e = e0 + t; e < e1; e += 256) {
    int k = keys[e] - lo;
    if ((unsigned)k < (unsigned)HSEG)
      atomicAdd(&bins[k >> 2], 1u << ((k & 3) * 8));
  }
  __syncthreads();
  unsigned* out = partial + (size_t)(z * HC + c) * (SP >> 2) + (lo >> 2);
  for (int i = t; i < HSEG / 4; i += 256) out[i] = bins[i];
}

__global__ void k_histred(const u8* __restrict__ partial, float* __restrict__ dinv,
                          int* __restrict__ hist, int N, int SP) {
  int n = blockIdx.x * 256 + threadIdx.x;
  if (n >= N) return;
  int a = 0, b = 0;
  for (int c = 0; c < HC; c++) a += partial[(size_t)c * SP + n];
  for (int c = 0; c < HC; c++) b += partial[(size_t)(HC + c) * SP + n];
  dinv[n] = a > 0 ? rsqrtf((float)a) : 0.f;
  hist[n] = b;
}

// ---- hierarchical scan over PADDED counts ----
#define SC_CHUNK 400

__device__ __forceinline__ int lds_incl_scan256(int* lds, int t, int v) {
  lds[t] = v; __syncthreads();
  for (int off = 1; off < 256; off <<= 1) {
    int u = (t >= off) ? lds[t - off] : 0;
    __syncthreads();
    lds[t] += u;
    __syncthreads();
  }
  return lds[t];
}

__device__ __forceinline__ int padcnt(int h) { return (h + (ROWPAD - 1)) & ~(ROWPAD - 1); }

__global__ void k_scan1(const int* __restrict__ hist, int* __restrict__ bsum, int N) {
  __shared__ int lds[256];
  int b = blockIdx.x, t = threadIdx.x;
  int lo = b * SC_CHUNK;
  int hi = lo + SC_CHUNK; if (hi > N) hi = N;
  int i0 = lo + t * 2;
  int s = 0;
  if (i0 < hi) s += padcnt(hist[i0]);
  if (i0 + 1 < hi) s += padcnt(hist[i0 + 1]);
  int incl = lds_incl_scan256(lds, t, s);
  if (t == 255) bsum[b] = incl;
}

__global__ void k_scan2(const int* __restrict__ bsum, int* __restrict__ bbase, int nb) {
  __shared__ int lds[256];
  int t = threadIdx.x;
  int v = (t < nb) ? bsum[t] : 0;
  int incl = lds_incl_scan256(lds, t, v);
  if (t < nb) bbase[t] = incl - v;
  if (t == nb - 1) bbase[nb] = incl;
}

__global__ void k_scan3(const int* __restrict__ hist, const int* __restrict__ bbase,
                        int* __restrict__ offs, int N, int nb) {
  __shared__ int lds[256];
  int b = blockIdx.x, t = threadIdx.x;
  int lo = b * SC_CHUNK;
  int hi = lo + SC_CHUNK; if (hi > N) hi = N;
  int i0 = lo + t * 2;
  int h0 = (i0 < hi) ? padcnt(hist[i0]) : 0;
  int h1 = (i0 + 1 < hi) ? padcnt(hist[i0 + 1]) : 0;
  int s = h0 + h1;
  int incl = lds_incl_scan256(lds, t, s);
  int run = bbase[b] + incl - s;
  if (i0 < hi) offs[i0] = run;
  if (i0 + 1 < hi) offs[i0 + 1] = run + h0;
  if (b == 0 && t == 0) offs[N] = bbase[nb];
}

// ---------------- two-phase binned scatter ----------------
__global__ void k_bcnt(const int* __restrict__ hist, int* __restrict__ bcnt, int N) {
  __shared__ int red[256];
  int b = blockIdx.x, t = threadIdx.x;
  int n = (b << 8) + t;
  red[t] = (n < N) ? hist[n] : 0;
  __syncthreads();
  for (int off = 128; off; off >>= 1) {
    if (t < off) red[t] += red[t + off];
    __syncthreads();
  }
  if (t == 0) bcnt[b] = red[0];
}

__global__ void k_bscan(const int* __restrict__ bcnt, int* __restrict__ bbase2,
                        int* __restrict__ bcur, int nb) {
  __shared__ int lds[256];
  int t = threadIdx.x;
  int i0 = 2 * t, i1 = 2 * t + 1;
  int v0 = (i0 < nb) ? bcnt[i0] : 0;
  int v1 = (i1 < nb) ? bcnt[i1] : 0;
  int s = v0 + v1;
  int incl = lds_incl_scan256(lds, t, s);
  int ex = incl - s;
  if (i0 < nb) { bbase2[i0] = ex; bcur[i0] = ex; }
  if (i1 < nb) { bbase2[i1] = ex + v0; bcur[i1] = ex + v0; }
  if (t == 255) bbase2[nb] = incl;
}

__global__ void k_part(const int* __restrict__ src, const int* __restrict__ dst,
                       int* __restrict__ bcur, int2* __restrict__ ebuck, int E) {
  __shared__ int lcnt[MAXB], lbase[MAXB];
  int t = threadIdx.x;
  for (int i = t; i < MAXB; i += 256) lcnt[i] = 0;
  __syncthreads();
  int ck = (E + gridDim.x - 1) / gridDim.x;
  int e0 = blockIdx.x * ck, e1 = e0 + ck; if (e1 > E) e1 = E;
  for (int e = e0 + t; e < e1; e += 256) atomicAdd(&lcnt[dst[e] >> 8], 1);
  __syncthreads();
  for (int i = t; i < MAXB; i += 256) {
    int c = lcnt[i];
    lbase[i] = c ? atomicAdd(&bcur[i], c) : 0;
    lcnt[i] = 0;
  }
  __syncthreads();
  for (int e = e0 + t; e < e1; e += 256) {
    int d = dst[e];
    int b = d >> 8;
    int ofs = atomicAdd(&lcnt[b], 1);
    int2 r; r.x = src[e]; r.y = d;
    ebuck[lbase[b] + ofs] = r;
  }
}

__global__ void k_place(const int2* __restrict__ ebuck, const int* __restrict__ bbase2,
                        const int* __restrict__ offs, const float* __restrict__ dinv,
                        int2* __restrict__ erec, int N) {
  __shared__ int lcur[256];
  int b = blockIdx.x, t = threadIdx.x;
  lcur[t] = 0;
  __syncthreads();
  int nlo = b << 8;
  int e0 = bbase2[b], e1 = bbase2[b + 1];
  for (int e = e0 + t; e < e1; e += 256) {
    int2 sd = ebuck[e];
    int s = sd.x, d = sd.y;
    int ofs = atomicAdd(&lcur[d - nlo], 1);
    int2 r;
    r.x = s;
    r.y = __float_as_int(-dinv[s] * dinv[d]);
    erec[offs[d] + ofs] = r;
  }
  __syncthreads();
  int n = nlo + t;
  if (n < N) {
    int st = offs[n] + lcur[t];
    int en = offs[n + 1];
    int2 z; z.x = 0; z.y = 0;
    for (int p = st; p < en; p++) erec[p] = z;
  }
}

// ---------------- propagation (padded CSR, bf16 features, scalar record loads) ----------------
__global__ void k_prop64b(const u16* __restrict__ gf, const float* __restrict__ gab,
                          const u16* __restrict__ oldv, const float* __restrict__ oab,
                          u16* __restrict__ outv, const int* __restrict__ offs,
                          const v4i* __restrict__ erec4, int N, int recur) {
  int wid = (blockIdx.x * 256 + threadIdx.x) >> 6;
  int lane = threadIdx.x & 63;
  if (wid >= N) return;
  int row = __builtin_amdgcn_readfirstlane(wid);  // wave-uniform -> scalar loads for records
  int q = offs[row] >> 1, qe = offs[row + 1] >> 1;
  float acc = 0.f, sw = 0.f;
  for (; q + 8 <= qe; q += 8) {  // 16 records
    v4i m[8];
#pragma unroll
    for (int j = 0; j < 8; j++) m[j] = erec4[q + j];
    u16 g[16];
#pragma unroll
    for (int j = 0; j < 8; j++) {
      g[2 * j]     = gf[(size_t)m[j].x * 64 + lane];
      g[2 * j + 1] = gf[(size_t)m[j].z * 64 + lane];
    }
#pragma unroll
    for (int j = 0; j < 8; j++) {
      float w0 = __int_as_float(m[j].y), w1 = __int_as_float(m[j].w);
      acc += w0 * b2f(g[2 * j]) + w1 * b2f(g[2 * j + 1]);
      sw += w0 + w1;
    }
  }
  if (q < qe) {  // exactly 8 records
    v4i m[4];
#pragma unroll
    for (int j = 0; j < 4; j++) m[j] = erec4[q + j];
    u16 g[8];
#pragma unroll
    for (int j = 0; j < 4; j++) {
      g[2 * j]     = gf[(size_t)m[j].x * 64 + lane];
      g[2 * j + 1] = gf[(size_t)m[j].z * 64 + lane];
    }
#pragma unroll
    for (int j = 0; j < 4; j++) {
      float w0 = __int_as_float(m[j].y), w1 = __int_as_float(m[j].w);
      acc += w0 * b2f(g[2 * j]) + w1 * b2f(g[2 * j + 1]);
      sw += w0 + w1;
    }
  }
  float res = acc;
  if (gab) res = gab[lane] * acc + gab[64 + lane] * sw;
  int idx = wid * 64 + lane;
  if (recur) {
    float o = b2f(oldv[idx]);
    if (oab) o = oab[lane] * o + oab[64 + lane];
    res = 2.f * res - o;
  }
  outv[idx] = f2b(res);
}

// F=3 f32 variant (layer 1)
__global__ void k_prop3(const float* __restrict__ gf, const float* __restrict__ oldv,
                        float* __restrict__ outv, const int* __restrict__ offs,
                        const v4i* __restrict__ erec4, int N, int recur) {
  int n = blockIdx.x * 256 + threadIdx.x;
  if (n >= N) return;
  int q = offs[n] >> 1, qe = offs[n + 1] >> 1;
  float a0 = 0.f, a1 = 0.f, a2 = 0.f;
  for (; q < qe; q += 4) {
    v4i m[4];
#pragma unroll
    for (int j = 0; j < 4; j++) m[j] = erec4[q + j];
#pragma unroll
    for (int j = 0; j < 4; j++) {
      float w0 = __int_as_float(m[j].y), w1 = __int_as_float(m[j].w);
      int s0 = m[j].x, s1 = m[j].z;
      a0 += w0 * gf[s0 * 3 + 0] + w1 * gf[s1 * 3 + 0];
      a1 += w0 * gf[s0 * 3 + 1] + w1 * gf[s1 * 3 + 1];
      a2 += w0 * gf[s0 * 3 + 2] + w1 * gf[s1 * 3 + 2];
    }
  }
  if (recur) {
    a0 = 2.f * a0 - oldv[n * 3 + 0];
    a1 = 2.f * a1 - oldv[n * 3 + 1];
    a2 = 2.f * a2 - oldv[n * 3 + 2];
  }
  outv[n * 3 + 0] = a0;
  outv[n * 3 + 1] = a1;
  outv[n * 3 + 2] = a2;
}

// ---------------- merged 4-term combine: out = bias + Σp Tp@Wp ----------------
// Natural-layout staging (b128 writes, conflict-free); i-unrolled-by-4 b128 reads.
template <int FOUT, bool OUTBF, bool DOBN>
__global__ void k_combine4(void* outp, const u16* T0, const float* __restrict__ ab,
                           const u16* __restrict__ T1, const u16* __restrict__ T2,
                           const u16* __restrict__ T3, const float* __restrict__ W,
                           const float* __restrict__ bias, float* __restrict__ gs, int N) {
  constexpr int PADN = 68;
  constexpr int PADW = FOUT + 4;
  __shared__ float TxS[64 * PADN];
  __shared__ float WS[64 * PADW];
  int tid = threadIdx.x;
  int n_base = blockIdx.x * 64;
  int tj = tid % (FOUT / 4);
  int tn = tid / (FOUT / 4);  // 0..15
  int j0 = tj * 4, n0 = tn * 4;

  float acc[4][4];
  {
    float4 b = *(const float4*)(bias + j0);
    for (int a = 0; a < 4; a++) { acc[a][0] = b.x; acc[a][1] = b.y; acc[a][2] = b.z; acc[a][3] = b.w; }
  }

  const u16* Ts[4] = {T0, T1, T2, T3};
  for (int p = 0; p < 4; p++) {
    if (p) __syncthreads();
    for (int idx = tid; idx < 64 * FOUT / 4; idx += blockDim.x) {
      int r = idx / (FOUT / 4), c4 = idx % (FOUT / 4);
      float4 w = *(const float4*)(W + p * 64 * FOUT + r * FOUT + c4 * 4);
      *(float4*)(&WS[r * PADW + c4 * 4]) = w;
    }
    for (int idx = tid; idx < 64 * 16; idx += blockDim.x) {
      int r = idx / 16, c4 = idx % 16;
      int n = n_base + r;
      float4 t = make_float4(0.f, 0.f, 0.f, 0.f);
      if (n < N) {
        ushort4 u = *(const ushort4*)(Ts[p] + (size_t)n * 64 + c4 * 4);
        t.x = b2f(u.x); t.y = b2f(u.y); t.z = b2f(u.z); t.w = b2f(u.w);
      }
      if (p == 0 && ab) {
        float4 a4 = *(const float4*)(ab + c4 * 4);
        float4 b4 = *(const float4*)(ab + 64 + c4 * 4);
        t.x = t.x * a4.x + b4.x;
        t.y = t.y * a4.y + b4.y;
        t.z = t.z * a4.z + b4.z;
        t.w = t.w * a4.w + b4.w;
      }
      *(float4*)(&TxS[r * PADN + c4 * 4]) = t;
    }
    __syncthreads();
#pragma unroll 4
    for (int i4 = 0; i4 < 16; i4++) {
      float4 t0 = *(const float4*)(&TxS[(n0 + 0) * PADN + i4 * 4]);
      float4 t1 = *(const float4*)(&TxS[(n0 + 1) * PADN + i4 * 4]);
      float4 t2 = *(const float4*)(&TxS[(n0 + 2) * PADN + i4 * 4]);
      float4 t3 = *(const float4*)(&TxS[(n0 + 3) * PADN + i4 * 4]);
      float4 w0 = *(const float4*)(&WS[(i4 * 4 + 0) * PADW + j0]);
      float4 w1 = *(const float4*)(&WS[(i4 * 4 + 1) * PADW + j0]);
      float4 w2 = *(const float4*)(&WS[(i4 * 4 + 2) * PADW + j0]);
      float4 w3 = *(const float4*)(&WS[(i4 * 4 + 3) * PADW + j0]);
      acc[0][0] += t0.x * w0.x + t0.y * w1.x + t0.z * w2.x + t0.w * w3.x;
      acc[0][1] += t0.x * w0.y + t0.y * w1.y + t0.z * w2.y + t0.w * w3.y;
      acc[0][2] += t0.x * w0.z + t0.y * w1.z + t0.z * w2.z + t0.w * w3.z;
      acc[0][3] += t0.x * w0.w + t0.y * w1.w + t0.z * w2.w + t0.w * w3.w;
      acc[1][0] += t1.x * w0.x + t1.y * w1.x + t1.z * w2.x + t1.w * w3.x;
      acc[1][1] += t1.x * w0.y + t1.y * w1.y + t1.z * w2.y + t1.w * w3.y;
      acc[1][2] += t1.x * w0.z + t1.y * w1.z + t1.z * w2.z + t1.w * w3.z;
      acc[1][3] += t1.x * w0.w + t1.y * w1.w + t1.z * w2.w + t1.w * w3.w;
      acc[2][0] += t2.x * w0.x + t2.y * w1.x + t2.z * w2.x + t2.w * w3.x;
      acc[2][1] += t2.x * w0.y + t2.y * w1.y + t2.z * w2.y + t2.w * w3.y;
      acc[2][2] += t2.x * w0.z + t2.y * w1.z + t2.z * w2.z + t2.w * w3.z;
      acc[2][3] += t2.x * w0.w + t2.y * w1.w + t2.z * w2.w + t2.w * w3.w;
      acc[3][0] += t3.x * w0.x + t3.y * w1.x + t3.z * w2.x + t3.w * w3.x;
      acc[3][1] += t3.x * w0.y + t3.y * w1.y + t3.z * w2.y + t3.w * w3.y;
      acc[3][2] += t3.x * w0.z + t3.y * w1.z + t3.z * w2.z + t3.w * w3.z;
      acc[3][3] += t3.x * w0.w + t3.y * w1.w + t3.z * w2.w + t3.w * w3.w;
    }
  }

  if (DOBN) {
    float s[4] = {0.f, 0.f, 0.f, 0.f}, q[4] = {0.f, 0.f, 0.f, 0.f};
    for (int a = 0; a < 4; a++) {
      int n = n_base + n0 + a;
      if (n < N) {
        for (int k = 0; k < 4; k++) {
          float v = acc[a][k];
          v = v >= 0.f ? v : 0.01f * v;
          acc[a][k] = v;
          s[k] += v; q[k] += v * v;
        }
      }
    }
    __syncthreads();
    float* redS = TxS;
    float* redQ = TxS + 1024;
    for (int k = 0; k < 4; k++) {
      redS[(j0 + k) * 16 + tn] = s[k];
      redQ[(j0 + k) * 16 + tn] = q[k];
    }
    __syncthreads();
    if (tid < 64) {
      float a_ = 0.f, b_ = 0.f;
      for (int w = 0; w < 16; w++) { a_ += redS[tid * 16 + w]; b_ += redQ[tid * 16 + w]; }
      atomicAdd(&gs[tid], a_);
      atomicAdd(&gs[64 + tid], b_);
    }
  }

  for (int a = 0; a < 4; a++) {
    int n = n_base + n0 + a;
    if (n < N) {
      if (OUTBF) {
        ushort4 o;
        o.x = f2b(acc[a][0]); o.y = f2b(acc[a][1]); o.z = f2b(acc[a][2]); o.w = f2b(acc[a][3]);
        *(ushort4*)((u16*)outp + (size_t)n * FOUT + j0) = o;
      } else {
        *(float4*)((float*)outp + (size_t)n * FOUT + j0) =
            make_float4(acc[a][0], acc[a][1], acc[a][2], acc[a][3]);
      }
    }
  }
}

// ---------------- merged layer-1 combine (Fin=3, f32 in, bf16 out) ----------------
__global__ void k_combine1(u16* __restrict__ H, const float* __restrict__ x,
                           const float* __restrict__ t1, const float* __restrict__ t2,
                           const float* __restrict__ t3, const float* __restrict__ W,
                           const float* __restrict__ bias, int N) {
  __shared__ float ws[768];  // [4][3][64]
  int tid = threadIdx.x;
  for (int i = tid; i < 768; i += 256) ws[i] = W[i];
  __syncthreads();
  int n = blockIdx.x * 4 + tid / 64;
  int j = tid % 64;
  if (n >= N) return;
  float acc = bias[j];
  const float* xs[4] = {x, t1, t2, t3};
#pragma unroll
  for (int p = 0; p < 4; p++)
#pragma unroll
    for (int i = 0; i < 3; i++)
      acc += xs[p][n * 3 + i] * ws[p * 192 + i * 64 + j];
  H[(size_t)n * 64 + j] = f2b(acc);
}

// ---------------- LeakyReLU + BN stats (layer 1: bf16 in-place, atomic slot) ----------------
#define BN_GRID 400
__global__ void k_bnstats(u16* __restrict__ H, float* __restrict__ gs, int N) {
  __shared__ float red[256 * 8];
  int t = threadIdx.x;
  int f4 = t & 15, r = t >> 4;
  float s0 = 0.f, s1 = 0.f, s2 = 0.f, s3 = 0.f;
  float q0 = 0.f, q1 = 0.f, q2 = 0.f, q3 = 0.f;
  for (int n = blockIdx.x * 16 + r; n < N; n += BN_GRID * 16) {
    ushort4 u = *(ushort4*)(H + (size_t)n * 64 + f4 * 4);
    float vx = b2f(u.x), vy = b2f(u.y), vz = b2f(u.z), vw = b2f(u.w);
    vx = vx >= 0.f ? vx : 0.01f * vx;
    vy = vy >= 0.f ? vy : 0.01f * vy;
    vz = vz >= 0.f ? vz : 0.01f * vz;
    vw = vw >= 0.f ? vw : 0.01f * vw;
    ushort4 o; o.x = f2b(vx); o.y = f2b(vy); o.z = f2b(vz); o.w = f2b(vw);
    *(ushort4*)(H + (size_t)n * 64 + f4 * 4) = o;
    s0 += vx; s1 += vy; s2 += vz; s3 += vw;
    q0 += vx * vx; q1 += vy * vy; q2 += vz * vz; q3 += vw * vw;
  }
  float* rp = &red[t * 8];
  rp[0] = s0; rp[1] = s1; rp[2] = s2; rp[3] = s3;
  rp[4] = q0; rp[5] = q1; rp[6] = q2; rp[7] = q3;
  __syncthreads();
  if (t < 64) {
    int f4g = t >> 2, k = t & 3;
    float a = 0.f, b = 0.f;
    for (int rr = 0; rr < 16; rr++) {
      a += red[(rr * 16 + f4g) * 8 + k];
      b += red[(rr * 16 + f4g) * 8 + 4 + k];
    }
    atomicAdd(&gs[t], a);
    atomicAdd(&gs[64 + t], b);
  }
}

__global__ void k_bnfinal2(const float* __restrict__ gs, const float* __restrict__ g,
                           const float* __restrict__ bt, float* __restrict__ ab, float Ninv) {
  int t = threadIdx.x;  // 64
  float mu = gs[t] * Ninv;
  float var = gs[64 + t] * Ninv - mu * mu;
  float a = g[t] / sqrtf(var + EPS_BN);
  ab[t] = a;
  ab[64 + t] = bt[t] - mu * a;
}

// ---------------- pooling (fused row L2-normalize) ----------------
__device__ __forceinline__ unsigned fkey(float x) {
  unsigned u = __float_as_uint(x);
  return (u & 0x80000000u) ? ~u : (u | 0x80000000u);
}
__device__ __forceinline__ float fdec(unsigned u) {
  return (u & 0x80000000u) ? __uint_as_float(u & 0x7FFFFFFFu) : __uint_as_float(~u);
}

#define POOL_CHUNK 512
__global__ void k_pool2(const float* __restrict__ H, const int* __restrict__ batch,
                        float* __restrict__ psum, unsigned* __restrict__ pmax,
                        unsigned* __restrict__ pmin, float* __restrict__ pcnt, int N) {
  int f = threadIdx.x & 31;
  int sub = threadIdx.x >> 5;
  int n0 = blockIdx.x * POOL_CHUNK;
  int n1 = n0 + POOL_CHUNK; if (n1 > N) n1 = N;
  int curg = -1;
  float s = 0.f, mx = -3.4e38f, mn = 3.4e38f, cnt = 0.f;
  for (int n = n0 + sub; n < n1; n += 8) {
    int g = batch[n];
    if (g != curg) {
      if (curg >= 0) {
        atomicAdd(&psum[curg * 32 + f], s);
        atomicMax(&pmax[curg * 32 + f], fkey(mx));
        atomicMin(&pmin[curg * 32 + f], fkey(mn));
        if (f == 0) atomicAdd(&pcnt[curg], cnt);
      }
      curg = g; s = 0.f; mx = -3.4e38f; mn = 3.4e38f; cnt = 0.f;
    }
    float v = H[n * 32 + f];
    float ss = v * v;
    for (int off = 16; off; off >>= 1) ss += __shfl_xor(ss, off, 32);
    v /= fmaxf(sqrtf(ss), 1e-12f);
    s += v; mx = fmaxf(mx, v); mn = fminf(mn, v); cnt += 1.f;
  }
  if (curg >= 0) {
    atomicAdd(&psum[curg * 32 + f], s);
    atomicMax(&pmax[curg * 32 + f], fkey(mx));
    atomicMin(&pmin[curg * 32 + f], fkey(mn));
    if (f == 0) atomicAdd(&pcnt[curg], cnt);
  }
}

__global__ void k_poolfin(const float* __restrict__ psum, const unsigned* __restrict__ pmax,
                          const unsigned* __restrict__ pmin, const float* __restrict__ pcnt,
                          float* __restrict__ out) {
  int g = blockIdx.x, f = threadIdx.x;
  float s = psum[g * 32 + f];
  float c = fmaxf(pcnt[g], 1.0f);
  out[g * 128 + f] = s / c;
  out[g * 128 + 32 + f] = fdec(pmax[g * 32 + f]);
  out[g * 128 + 64 + f] = fdec(pmin[g * 32 + f]);
  out[g * 128 + 96 + f] = s;
}

// ---------------- host ----------------

extern "C" void kernel_launch(void* const* d_in, const int* in_sizes, int n_in,
                              void* d_out, int out_size, void* d_ws, size_t ws_size,
                              hipStream_t stream) {
  const float* x   = (const float*)d_in[0];
  const int*   ei  = (const int*)d_in[1];
  const int*   bat = (const int*)d_in[2];
  const float* W1  = (const float*)d_in[3];  const float* bc1 = (const float*)d_in[4];
  const float* W2  = (const float*)d_in[5];  const float* bc2 = (const float*)d_in[6];
  const float* W3  = (const float*)d_in[7];  const float* bc3 = (const float*)d_in[8];
  const float* W4  = (const float*)d_in[9];  const float* bc4 = (const float*)d_in[10];
  const float* g1  = (const float*)d_in[11]; const float* bt1 = (const float*)d_in[12];
  const float* g2  = (const float*)d_in[13]; const float* bt2 = (const float*)d_in[14];
  const float* g3  = (const float*)d_in[15]; const float* bt3 = (const float*)d_in[16];

  const int N = in_sizes[0] / 3;
  const int E = in_sizes[1] / 2;
  const int* src = ei;
  const int* dst = ei + E;
  const size_t Epad = (size_t)E + (size_t)(ROWPAD - 1) * N + 64;

  float* base = (float*)d_ws;
  size_t o = 0;
  auto alloc = [&](size_t n) -> float* {
    float* p = base + o;
    o += (n + 63) & ~(size_t)63;
    return p;
  };
  // zeroed region (contiguous from d_ws start):
  float* psum   = alloc(64 * 32);
  float* pcnt   = alloc(64);
  unsigned* pmax = (unsigned*)alloc(64 * 32);
  float* bnacc  = alloc(3 * 128);  // per-layer [sum64][sumsq64]
  size_t zero_elems = o;
  // 0xFF region:
  unsigned* pmin = (unsigned*)alloc(64 * 32);
  // uninitialized (fully overwritten before read):
  int2*  erec  = (int2*)alloc(2 * Epad);  // pad slots written by k_place
  float* dinv  = alloc(N);
  int*   hist  = (int*)alloc(N);
  int*   offs  = (int*)alloc(N + 1);
  int*   bsum  = (int*)alloc(256);
  int*   bbase = (int*)alloc(257);
  int*   bcnt  = (int*)alloc(MAXB);
  int*   bbase2 = (int*)alloc(MAXB + 1);
  int*   bcur  = (int*)alloc(MAXB);
  float* ab    = alloc(128);
  float* t1f   = alloc(3 * (size_t)N);
  float* t2f   = alloc(3 * (size_t)N);
  float* t3f   = alloc(3 * (size_t)N);
  u16*   T0    = (u16*)alloc((size_t)N * 32);  // bf16 [N][64]
  u16*   T1    = (u16*)alloc((size_t)N * 32);
  u16*   T2    = (u16*)alloc((size_t)N * 32);
  u16*   T3    = (u16*)alloc((size_t)N * 32);
  float* C32   = alloc((size_t)N * 32);

  hipMemsetAsync(d_ws, 0, zero_elems * sizeof(float), stream);
  hipMemsetAsync(pmin, 0xFF, 64 * 32 * sizeof(unsigned), stream);

  const int NB = (N + 255) / 256;
  const int SB = (N + SC_CHUNK - 1) / SC_CHUNK;
  const int S  = (N + HSEG - 1) / HSEG;
  const int SP = S * HSEG;
  const int NBK = (N + 255) >> 8;
  unsigned* partial = (unsigned*)T0;  // alias: 2*HC*SP u8 (~16.8 MB) fits in T0+T1 (25.6 MB)
  int2* ebuck = (int2*)T2;            // alias: E int2 = 12.8 MB = T2 exactly

  k_histseg<<<dim3(S, HC, 2), 256, 0, stream>>>(src, dst, partial, E, SP);
  k_histred<<<NB, 256, 0, stream>>>((const u8*)partial, dinv, hist, N, SP);
  k_scan1<<<SB, 256, 0, stream>>>(hist, bsum, N);
  k_scan2<<<1, 256, 0, stream>>>(bsum, bbase, SB);
  k_scan3<<<SB, 256, 0, stream>>>(hist, bbase, offs, N, SB);
  k_bcnt<<<NBK, 256, 0, stream>>>(hist, bcnt, N);
  k_bscan<<<1, 256, 0, stream>>>(bcnt, bbase2, bcur, NBK);
  k_part<<<512, 256, 0, stream>>>(src, dst, bcur, ebuck, E);
  k_place<<<NBK, 256, 0, stream>>>(ebuck, bbase2, offs, dinv, erec, N);

  const int PB64 = (N * 64 + 255) / 256;
  const int TB = (N + 63) / 64;
  const v4i* erec4 = (const v4i*)erec;

  // ---- layer 1: Fin=3 -> 64 (f32 props, merged combine -> bf16 T0) ----
  k_prop3<<<NB, 256, 0, stream>>>(x, nullptr, t1f, offs, erec4, N, 0);
  k_prop3<<<NB, 256, 0, stream>>>(t1f, x, t2f, offs, erec4, N, 1);
  k_prop3<<<NB, 256, 0, stream>>>(t2f, t1f, t3f, offs, erec4, N, 1);
  k_combine1<<<(N + 3) / 4, 256, 0, stream>>>(T0, x, t1f, t2f, t3f, W1, bc1, N);
  k_bnstats<<<BN_GRID, 256, 0, stream>>>(T0, bnacc, N);
  k_bnfinal2<<<1, 64, 0, stream>>>(bnacc, g1, bt1, ab, 1.0f / N);

  // ---- layers 2 & 3: 64 -> 64 (fused lrelu+BN in combine) ----
  const float* Ws[2] = {W2, W3};
  const float* bs[2] = {bc2, bc3};
  const float* gs2[2] = {g2, g3};
  const float* bts[2] = {bt2, bt3};
  for (int L = 0; L < 2; L++) {
    const float* W = Ws[L];
    float* slot = bnacc + 128 * (L + 1);
    k_prop64b<<<PB64, 256, 0, stream>>>(T0, ab, nullptr, nullptr, T1, offs, erec4, N, 0);
    k_prop64b<<<PB64, 256, 0, stream>>>(T1, nullptr, T0, ab, T2, offs, erec4, N, 1);
    k_prop64b<<<PB64, 256, 0, stream>>>(T2, nullptr, T1, nullptr, T3, offs, erec4, N, 1);
    k_combine4<64, true, true><<<TB, 256, 0, stream>>>(T0, T0, ab, T1, T2, T3, W, bs[L], slot, N);
    k_bnfinal2<<<1, 64, 0, stream>>>(slot, gs2[L], bts[L], ab, 1.0f / N);
  }

  // ---- layer 4: 64 -> 32 (f32 out C32) ----
  k_prop64b<<<PB64, 256, 0, stream>>>(T0, ab, nullptr, nullptr, T1, offs, erec4, N, 0);
  k_prop64b<<<PB64, 256, 0, stream>>>(T1, nullptr, T0, ab, T2, offs, erec4, N, 1);
  k_prop64b<<<PB64, 256, 0, stream>>>(T2, nullptr, T1, nullptr, T3, offs, erec4, N, 1);
  k_combine4<32, false, false><<<TB, 128, 0, stream>>>(C32, T0, ab, T1, T2, T3, W4, bc4, nullptr, N);

  // ---- pool (L2-normalize fused) ----
  k_pool2<<<(N + POOL_CHUNK - 1) / POOL_CHUNK, 256, 0, stream>>>(C32, bat, psum, pmax, pmin, pcnt, N);
  k_poolfin<<<64, 32, 0, stream>>>(psum, pmax, pmin, pcnt, (float*)d_out);
}

// Round 13
// 817.299 us; speedup vs baseline: 1.0598x; 1.0598x over previous
//
#include <hip/hip_runtime.h>

#define EPS_BN 1e-5f
#define ROWPAD 8    // CSR rows padded to multiple of 8 edges (src=0,w=0 filler)
#define HSEG 32768  // histogram bins per segment (packed u8 -> 32 KB LDS)
#define HC 64       // histogram edge-chunks
#define MAXB 512    // max dst-buckets (256 nodes each)

typedef unsigned short u16;
typedef unsigned char u8;
typedef int v4i __attribute__((ext_vector_type(4)));
typedef short bf8v __attribute__((ext_vector_type(8)));   // 8 bf16 (4 VGPRs) MFMA A/B frag
typedef float f4v __attribute__((ext_vector_type(4)));    // MFMA C/D frag

__device__ __forceinline__ float b2f(u16 u) {
  return __uint_as_float(((unsigned)u) << 16);
}
__device__ __forceinline__ u16 f2b(float f) {  // RTNE
  unsigned u = __float_as_uint(f);
  u += 0x7fffu + ((u >> 16) & 1u);
  return (u16)(u >> 16);
}

// ---------------- preprocessing: packed-u8 LDS segmented histograms ----------------
__global__ void k_histseg(const int* __restrict__ src, const int* __restrict__ dst,
                          unsigned* __restrict__ partial, int E, int SP) {
  __shared__ unsigned bins[HSEG / 4];
  int s = blockIdx.x, c = blockIdx.y, z = blockIdx.z;
  int t = threadIdx.x;
  for (int i = t; i < HSEG / 4; i += 256) bins[i] = 0;
  __syncthreads();
  const int* keys = z ? dst : src;
  int lo = s * HSEG;
  int ck = (E + HC - 1) / HC;
  int e0 = c * ck, e1 = e0 + ck; if (e1 > E) e1 = E;
  for (int e = e0 + t; e < e1; e += 256) {
    int k = keys[e] - lo;
    if ((unsigned)k < (unsigned)HSEG)
      atomicAdd(&bins[k >> 2], 1u << ((k & 3) * 8));
  }
  __syncthreads();
  unsigned* out = partial + (size_t)(z * HC + c) * (SP >> 2) + (lo >> 2);
  for (int i = t; i < HSEG / 4; i += 256) out[i] = bins[i];
}

__global__ void k_histred(const u8* __restrict__ partial, float* __restrict__ dinv,
                          int* __restrict__ hist, int N, int SP) {
  int n = blockIdx.x * 256 + threadIdx.x;
  if (n >= N) return;
  int a = 0, b = 0;
  for (int c = 0; c < HC; c++) a += partial[(size_t)c * SP + n];
  for (int c = 0; c < HC; c++) b += partial[(size_t)(HC + c) * SP + n];
  dinv[n] = a > 0 ? rsqrtf((float)a) : 0.f;
  hist[n] = b;
}

// ---- hierarchical scan over PADDED counts ----
#define SC_CHUNK 400

__device__ __forceinline__ int lds_incl_scan256(int* lds, int t, int v) {
  lds[t] = v; __syncthreads();
  for (int off = 1; off < 256; off <<= 1) {
    int u = (t >= off) ? lds[t - off] : 0;
    __syncthreads();
    lds[t] += u;
    __syncthreads();
  }
  return lds[t];
}

__device__ __forceinline__ int padcnt(int h) { return (h + (ROWPAD - 1)) & ~(ROWPAD - 1); }

__global__ void k_scan1(const int* __restrict__ hist, int* __restrict__ bsum, int N) {
  __shared__ int lds[256];
  int b = blockIdx.x, t = threadIdx.x;
  int lo = b * SC_CHUNK;
  int hi = lo + SC_CHUNK; if (hi > N) hi = N;
  int i0 = lo + t * 2;
  int s = 0;
  if (i0 < hi) s += padcnt(hist[i0]);
  if (i0 + 1 < hi) s += padcnt(hist[i0 + 1]);
  int incl = lds_incl_scan256(lds, t, s);
  if (t == 255) bsum[b] = incl;
}

__global__ void k_scan2(const int* __restrict__ bsum, int* __restrict__ bbase, int nb) {
  __shared__ int lds[256];
  int t = threadIdx.x;
  int v = (t < nb) ? bsum[t] : 0;
  int incl = lds_incl_scan256(lds, t, v);
  if (t < nb) bbase[t] = incl - v;
  if (t == nb - 1) bbase[nb] = incl;
}

__global__ void k_scan3(const int* __restrict__ hist, const int* __restrict__ bbase,
                        int* __restrict__ offs, int N, int nb) {
  __shared__ int lds[256];
  int b = blockIdx.x, t = threadIdx.x;
  int lo = b * SC_CHUNK;
  int hi = lo + SC_CHUNK; if (hi > N) hi = N;
  int i0 = lo + t * 2;
  int h0 = (i0 < hi) ? padcnt(hist[i0]) : 0;
  int h1 = (i0 + 1 < hi) ? padcnt(hist[i0 + 1]) : 0;
  int s = h0 + h1;
  int incl = lds_incl_scan256(lds, t, s);
  int run = bbase[b] + incl - s;
  if (i0 < hi) offs[i0] = run;
  if (i0 + 1 < hi) offs[i0 + 1] = run + h0;
  if (b == 0 && t == 0) offs[N] = bbase[nb];
}

// ---------------- two-phase binned scatter ----------------
__global__ void k_bcnt(const int* __restrict__ hist, int* __restrict__ bcnt, int N) {
  __shared__ int red[256];
  int b = blockIdx.x, t = threadIdx.x;
  int n = (b << 8) + t;
  red[t] = (n < N) ? hist[n] : 0;
  __syncthreads();
  for (int off = 128; off; off >>= 1) {
    if (t < off) red[t] += red[t + off];
    __syncthreads();
  }
  if (t == 0) bcnt[b] = red[0];
}

__global__ void k_bscan(const int* __restrict__ bcnt, int* __restrict__ bbase2,
                        int* __restrict__ bcur, int nb) {
  __shared__ int lds[256];
  int t = threadIdx.x;
  int i0 = 2 * t, i1 = 2 * t + 1;
  int v0 = (i0 < nb) ? bcnt[i0] : 0;
  int v1 = (i1 < nb) ? bcnt[i1] : 0;
  int s = v0 + v1;
  int incl = lds_incl_scan256(lds, t, s);
  int ex = incl - s;
  if (i0 < nb) { bbase2[i0] = ex; bcur[i0] = ex; }
  if (i1 < nb) { bbase2[i1] = ex + v0; bcur[i1] = ex + v0; }
  if (t == 255) bbase2[nb] = incl;
}

__global__ void k_part(const int* __restrict__ src, const int* __restrict__ dst,
                       int* __restrict__ bcur, int2* __restrict__ ebuck, int E) {
  __shared__ int lcnt[MAXB], lbase[MAXB];
  int t = threadIdx.x;
  for (int i = t; i < MAXB; i += 256) lcnt[i] = 0;
  __syncthreads();
  int ck = (E + gridDim.x - 1) / gridDim.x;
  int e0 = blockIdx.x * ck, e1 = e0 + ck; if (e1 > E) e1 = E;
  for (int e = e0 + t; e < e1; e += 256) atomicAdd(&lcnt[dst[e] >> 8], 1);
  __syncthreads();
  for (int i = t; i < MAXB; i += 256) {
    int c = lcnt[i];
    lbase[i] = c ? atomicAdd(&bcur[i], c) : 0;
    lcnt[i] = 0;
  }
  __syncthreads();
  for (int e = e0 + t; e < e1; e += 256) {
    int d = dst[e];
    int b = d >> 8;
    int ofs = atomicAdd(&lcnt[b], 1);
    int2 r; r.x = src[e]; r.y = d;
    ebuck[lbase[b] + ofs] = r;
  }
}

__global__ void k_place(const int2* __restrict__ ebuck, const int* __restrict__ bbase2,
                        const int* __restrict__ offs, const float* __restrict__ dinv,
                        int2* __restrict__ erec, int N) {
  __shared__ int lcur[256];
  int b = blockIdx.x, t = threadIdx.x;
  lcur[t] = 0;
  __syncthreads();
  int nlo = b << 8;
  int e0 = bbase2[b], e1 = bbase2[b + 1];
  for (int e = e0 + t; e < e1; e += 256) {
    int2 sd = ebuck[e];
    int s = sd.x, d = sd.y;
    int ofs = atomicAdd(&lcur[d - nlo], 1);
    int2 r;
    r.x = s;
    r.y = __float_as_int(-dinv[s] * dinv[d]);
    erec[offs[d] + ofs] = r;
  }
  __syncthreads();
  int n = nlo + t;
  if (n < N) {
    int st = offs[n] + lcur[t];
    int en = offs[n + 1];
    int2 z; z.x = 0; z.y = 0;
    for (int p = st; p < en; p++) erec[p] = z;
  }
}

// ---------------- propagation (padded CSR, bf16 features, scalar record loads) ----------------
__global__ void k_prop64b(const u16* __restrict__ gf, const float* __restrict__ gab,
                          const u16* __restrict__ oldv, const float* __restrict__ oab,
                          u16* __restrict__ outv, const int* __restrict__ offs,
                          const v4i* __restrict__ erec4, int N, int recur) {
  int wid = (blockIdx.x * 256 + threadIdx.x) >> 6;
  int lane = threadIdx.x & 63;
  if (wid >= N) return;
  int row = __builtin_amdgcn_readfirstlane(wid);  // wave-uniform -> scalar loads for records
  int q = offs[row] >> 1, qe = offs[row + 1] >> 1;
  float acc = 0.f, sw = 0.f;
  for (; q + 8 <= qe; q += 8) {  // 16 records
    v4i m[8];
#pragma unroll
    for (int j = 0; j < 8; j++) m[j] = erec4[q + j];
    u16 g[16];
#pragma unroll
    for (int j = 0; j < 8; j++) {
      g[2 * j]     = gf[(size_t)m[j].x * 64 + lane];
      g[2 * j + 1] = gf[(size_t)m[j].z * 64 + lane];
    }
#pragma unroll
    for (int j = 0; j < 8; j++) {
      float w0 = __int_as_float(m[j].y), w1 = __int_as_float(m[j].w);
      acc += w0 * b2f(g[2 * j]) + w1 * b2f(g[2 * j + 1]);
      sw += w0 + w1;
    }
  }
  if (q < qe) {  // exactly 8 records
    v4i m[4];
#pragma unroll
    for (int j = 0; j < 4; j++) m[j] = erec4[q + j];
    u16 g[8];
#pragma unroll
    for (int j = 0; j < 4; j++) {
      g[2 * j]     = gf[(size_t)m[j].x * 64 + lane];
      g[2 * j + 1] = gf[(size_t)m[j].z * 64 + lane];
    }
#pragma unroll
    for (int j = 0; j < 4; j++) {
      float w0 = __int_as_float(m[j].y), w1 = __int_as_float(m[j].w);
      acc += w0 * b2f(g[2 * j]) + w1 * b2f(g[2 * j + 1]);
      sw += w0 + w1;
    }
  }
  float res = acc;
  if (gab) res = gab[lane] * acc + gab[64 + lane] * sw;
  int idx = wid * 64 + lane;
  if (recur) {
    float o = b2f(oldv[idx]);
    if (oab) o = oab[lane] * o + oab[64 + lane];
    res = 2.f * res - o;
  }
  outv[idx] = f2b(res);
}

// F=3 f32 variant (layer 1)
__global__ void k_prop3(const float* __restrict__ gf, const float* __restrict__ oldv,
                        float* __restrict__ outv, const int* __restrict__ offs,
                        const v4i* __restrict__ erec4, int N, int recur) {
  int n = blockIdx.x * 256 + threadIdx.x;
  if (n >= N) return;
  int q = offs[n] >> 1, qe = offs[n + 1] >> 1;
  float a0 = 0.f, a1 = 0.f, a2 = 0.f;
  for (; q < qe; q += 4) {
    v4i m[4];
#pragma unroll
    for (int j = 0; j < 4; j++) m[j] = erec4[q + j];
#pragma unroll
    for (int j = 0; j < 4; j++) {
      float w0 = __int_as_float(m[j].y), w1 = __int_as_float(m[j].w);
      int s0 = m[j].x, s1 = m[j].z;
      a0 += w0 * gf[s0 * 3 + 0] + w1 * gf[s1 * 3 + 0];
      a1 += w0 * gf[s0 * 3 + 1] + w1 * gf[s1 * 3 + 1];
      a2 += w0 * gf[s0 * 3 + 2] + w1 * gf[s1 * 3 + 2];
    }
  }
  if (recur) {
    a0 = 2.f * a0 - oldv[n * 3 + 0];
    a1 = 2.f * a1 - oldv[n * 3 + 1];
    a2 = 2.f * a2 - oldv[n * 3 + 2];
  }
  outv[n * 3 + 0] = a0;
  outv[n * 3 + 1] = a1;
  outv[n * 3 + 2] = a2;
}

// ---------------- weight prep: f32 [4][64][FOUT] -> bf16 [4][FOUT][64] (transposed) ----------------
__global__ void k_wprep(const float* __restrict__ W2, const float* __restrict__ W3,
                        const float* __restrict__ W4, u16* __restrict__ WT2,
                        u16* __restrict__ WT3, u16* __restrict__ WT4) {
  int tid = blockIdx.x * 256 + threadIdx.x;
  if (tid < 16384) {
    int p = tid >> 12, j = (tid >> 6) & 63, k = tid & 63;
    WT2[tid] = f2b(W2[p * 4096 + k * 64 + j]);
    WT3[tid] = f2b(W3[p * 4096 + k * 64 + j]);
  }
  if (tid < 8192) {
    int p = tid >> 11, j = (tid >> 6) & 31, k = tid & 63;
    WT4[tid] = f2b(W4[p * 2048 + k * 32 + j]);
  }
}

// ---------------- MFMA combine: out = bias2 + sum_p Tp @ Wp  (K=256, bf16 MFMA) ----------------
// A-frag: A[m=lane&15][k=quad*8+j] direct from T tables.
// B-frag: B[k][n=lane&15] from LDS-staged WT (bf16 [4][FOUT][64], row stride 72 u16).
// ab: fold per-k scale a[k] into p=0 rows at staging (b folded into bias2 by k_bnfinal3).
// C/D: col=lane&15, row=quad*4+reg.
template <int FOUT, bool OUTBF, bool DOBN>
__global__ void k_combine_m(void* outp, const u16* __restrict__ T0,
                            const u16* __restrict__ T1, const u16* __restrict__ T2,
                            const u16* __restrict__ T3, const u16* __restrict__ WTg,
                            const float* __restrict__ ab, const float* __restrict__ bias2,
                            float* __restrict__ gs, int N) {
  constexpr int RS = 72;  // u16 row stride (144 B: 16B-aligned, balanced banks)
  constexpr int NT = FOUT / 16;
  __shared__ u16 WS[4 * FOUT * RS];
  int tid = threadIdx.x;
  int wv = tid >> 6, lane = tid & 63;
  int col = lane & 15, quad = lane >> 4;
  int nb = blockIdx.x * 64 + wv * 16;

  // stage WT (4*FOUT rows x 64 u16), fold a[k] into p=0 rows
  for (int idx = tid; idx < 4 * FOUT * 8; idx += 256) {
    int row = idx >> 3, c = idx & 7;
    const u16* sp = WTg + row * 64 + c * 8;
    u16* dp = &WS[row * RS + c * 8];
    if (row < FOUT) {  // p == 0
#pragma unroll
      for (int i = 0; i < 8; i++) dp[i] = f2b(ab[c * 8 + i] * b2f(sp[i]));
    } else {
#pragma unroll
      for (int i = 0; i < 8; i++) dp[i] = sp[i];
    }
  }
  __syncthreads();

  f4v acc[NT];
#pragma unroll
  for (int t = 0; t < NT; t++) {
    float bv = bias2[t * 16 + col];
    acc[t][0] = bv; acc[t][1] = bv; acc[t][2] = bv; acc[t][3] = bv;
  }

  int node = nb + col;
  bool valid = node < N;
  const u16* Ts[4] = {T0, T1, T2, T3};
#pragma unroll
  for (int p = 0; p < 4; p++) {
    const u16* T = Ts[p];
#pragma unroll
    for (int kb = 0; kb < 64; kb += 32) {
      bf8v a;
      if (valid) {
        a = *(const bf8v*)(T + (size_t)node * 64 + kb + quad * 8);
      } else {
#pragma unroll
        for (int i = 0; i < 8; i++) a[i] = 0;
      }
#pragma unroll
      for (int t = 0; t < NT; t++) {
        bf8v b = *(const bf8v*)(&WS[(size_t)(p * FOUT + t * 16 + col) * RS + kb + quad * 8]);
        acc[t] = __builtin_amdgcn_mfma_f32_16x16x32_bf16(a, b, acc[t], 0, 0, 0);
      }
    }
  }

  if (DOBN) {
    float s[NT], q[NT];
#pragma unroll
    for (int t = 0; t < NT; t++) { s[t] = 0.f; q[t] = 0.f; }
#pragma unroll
    for (int t = 0; t < NT; t++)
#pragma unroll
      for (int r = 0; r < 4; r++) {
        int n2 = nb + quad * 4 + r;
        if (n2 < N) {
          float v = acc[t][r];
          v = v >= 0.f ? v : 0.01f * v;
          acc[t][r] = v;
          s[t] += v; q[t] += v * v;
        }
      }
    __syncthreads();
    float* redS = (float*)WS;
    float* redQ = redS + 1024;
#pragma unroll
    for (int t = 0; t < NT; t++) {
      redS[(t * 16 + col) * 16 + wv * 4 + quad] = s[t];
      redQ[(t * 16 + col) * 16 + wv * 4 + quad] = q[t];
    }
    __syncthreads();
    if (tid < FOUT) {
      float a_ = 0.f, b_ = 0.f;
      for (int w = 0; w < 16; w++) { a_ += redS[tid * 16 + w]; b_ += redQ[tid * 16 + w]; }
      atomicAdd(&gs[tid], a_);
      atomicAdd(&gs[64 + tid], b_);
    }
  }

#pragma unroll
  for (int t = 0; t < NT; t++)
#pragma unroll
    for (int r = 0; r < 4; r++) {
      int n2 = nb + quad * 4 + r;
      if (n2 < N) {
        int j = t * 16 + col;
        if (OUTBF) ((u16*)outp)[(size_t)n2 * FOUT + j] = f2b(acc[t][r]);
        else       ((float*)outp)[(size_t)n2 * FOUT + j] = acc[t][r];
      }
    }
}

// ---------------- merged layer-1 combine (Fin=3, f32 in, bf16 out) ----------------
__global__ void k_combine1(u16* __restrict__ H, const float* __restrict__ x,
                           const float* __restrict__ t1, const float* __restrict__ t2,
                           const float* __restrict__ t3, const float* __restrict__ W,
                           const float* __restrict__ bias, int N) {
  __shared__ float ws[768];  // [4][3][64]
  int tid = threadIdx.x;
  for (int i = tid; i < 768; i += 256) ws[i] = W[i];
  __syncthreads();
  int n = blockIdx.x * 4 + tid / 64;
  int j = tid % 64;
  if (n >= N) return;
  float acc = bias[j];
  const float* xs[4] = {x, t1, t2, t3};
#pragma unroll
  for (int p = 0; p < 4; p++)
#pragma unroll
    for (int i = 0; i < 3; i++)
      acc += xs[p][n * 3 + i] * ws[p * 192 + i * 64 + j];
  H[(size_t)n * 64 + j] = f2b(acc);
}

// ---------------- LeakyReLU + BN stats (layer 1: bf16 in-place, atomic slot) ----------------
#define BN_GRID 400
__global__ void k_bnstats(u16* __restrict__ H, float* __restrict__ gs, int N) {
  __shared__ float red[256 * 8];
  int t = threadIdx.x;
  int f4 = t & 15, r = t >> 4;
  float s0 = 0.f, s1 = 0.f, s2 = 0.f, s3 = 0.f;
  float q0 = 0.f, q1 = 0.f, q2 = 0.f, q3 = 0.f;
  for (int n = blockIdx.x * 16 + r; n < N; n += BN_GRID * 16) {
    ushort4 u = *(ushort4*)(H + (size_t)n * 64 + f4 * 4);
    float vx = b2f(u.x), vy = b2f(u.y), vz = b2f(u.z), vw = b2f(u.w);
    vx = vx >= 0.f ? vx : 0.01f * vx;
    vy = vy >= 0.f ? vy : 0.01f * vy;
    vz = vz >= 0.f ? vz : 0.01f * vz;
    vw = vw >= 0.f ? vw : 0.01f * vw;
    ushort4 o; o.x = f2b(vx); o.y = f2b(vy); o.z = f2b(vz); o.w = f2b(vw);
    *(ushort4*)(H + (size_t)n * 64 + f4 * 4) = o;
    s0 += vx; s1 += vy; s2 += vz; s3 += vw;
    q0 += vx * vx; q1 += vy * vy; q2 += vz * vz; q3 += vw * vw;
  }
  float* rp = &red[t * 8];
  rp[0] = s0; rp[1] = s1; rp[2] = s2; rp[3] = s3;
  rp[4] = q0; rp[5] = q1; rp[6] = q2; rp[7] = q3;
  __syncthreads();
  if (t < 64) {
    int f4g = t >> 2, k = t & 3;
    float a = 0.f, b = 0.f;
    for (int rr = 0; rr < 16; rr++) {
      a += red[(rr * 16 + f4g) * 8 + k];
      b += red[(rr * 16 + f4g) * 8 + 4 + k];
    }
    atomicAdd(&gs[t], a);
    atomicAdd(&gs[64 + t], b);
  }
}

// BN finalize + fold shift into next combine's bias:
// ab = (a,b); bias2[j] = bias_next[j] + sum_k b[k] * Wnext0[k*FOUTN + j]
__global__ void k_bnfinal3(const float* __restrict__ gs, const float* __restrict__ g,
                           const float* __restrict__ bt, const float* __restrict__ Wn,
                           const float* __restrict__ bn, float* __restrict__ ab,
                           float* __restrict__ bias2, float Ninv, int FOUTN) {
  int t = threadIdx.x;  // 64
  float mu = gs[t] * Ninv;
  float var = gs[64 + t] * Ninv - mu * mu;
  float a = g[t] / sqrtf(var + EPS_BN);
  float b = bt[t] - mu * a;
  ab[t] = a;
  ab[64 + t] = b;
  __shared__ float bsh[64];
  bsh[t] = b;
  __syncthreads();
  for (int j = t; j < FOUTN; j += 64) {
    float s = bn[j];
    for (int k = 0; k < 64; k++) s += bsh[k] * Wn[k * FOUTN + j];
    bias2[j] = s;
  }
}

// ---------------- pooling (fused row L2-normalize) ----------------
__device__ __forceinline__ unsigned fkey(float x) {
  unsigned u = __float_as_uint(x);
  return (u & 0x80000000u) ? ~u : (u | 0x80000000u);
}
__device__ __forceinline__ float fdec(unsigned u) {
  return (u & 0x80000000u) ? __uint_as_float(u & 0x7FFFFFFFu) : __uint_as_float(~u);
}

#define POOL_CHUNK 512
__global__ void k_pool2(const float* __restrict__ H, const int* __restrict__ batch,
                        float* __restrict__ psum, unsigned* __restrict__ pmax,
                        unsigned* __restrict__ pmin, float* __restrict__ pcnt, int N) {
  int f = threadIdx.x & 31;
  int sub = threadIdx.x >> 5;
  int n0 = blockIdx.x * POOL_CHUNK;
  int n1 = n0 + POOL_CHUNK; if (n1 > N) n1 = N;
  int curg = -1;
  float s = 0.f, mx = -3.4e38f, mn = 3.4e38f, cnt = 0.f;
  for (int n = n0 + sub; n < n1; n += 8) {
    int g = batch[n];
    if (g != curg) {
      if (curg >= 0) {
        atomicAdd(&psum[curg * 32 + f], s);
        atomicMax(&pmax[curg * 32 + f], fkey(mx));
        atomicMin(&pmin[curg * 32 + f], fkey(mn));
        if (f == 0) atomicAdd(&pcnt[curg], cnt);
      }
      curg = g; s = 0.f; mx = -3.4e38f; mn = 3.4e38f; cnt = 0.f;
    }
    float v = H[n * 32 + f];
    float ss = v * v;
    for (int off = 16; off; off >>= 1) ss += __shfl_xor(ss, off, 32);
    v /= fmaxf(sqrtf(ss), 1e-12f);
    s += v; mx = fmaxf(mx, v); mn = fminf(mn, v); cnt += 1.f;
  }
  if (curg >= 0) {
    atomicAdd(&psum[curg * 32 + f], s);
    atomicMax(&pmax[curg * 32 + f], fkey(mx));
    atomicMin(&pmin[curg * 32 + f], fkey(mn));
    if (f == 0) atomicAdd(&pcnt[curg], cnt);
  }
}

__global__ void k_poolfin(const float* __restrict__ psum, const unsigned* __restrict__ pmax,
                          const unsigned* __restrict__ pmin, const float* __restrict__ pcnt,
                          float* __restrict__ out) {
  int g = blockIdx.x, f = threadIdx.x;
  float s = psum[g * 32 + f];
  float c = fmaxf(pcnt[g], 1.0f);
  out[g * 128 + f] = s / c;
  out[g * 128 + 32 + f] = fdec(pmax[g * 32 + f]);
  out[g * 128 + 64 + f] = fdec(pmin[g * 32 + f]);
  out[g * 128 + 96 + f] = s;
}

// ---------------- host ----------------

extern "C" void kernel_launch(void* const* d_in, const int* in_sizes, int n_in,
                              void* d_out, int out_size, void* d_ws, size_t ws_size,
                              hipStream_t stream) {
  const float* x   = (const float*)d_in[0];
  const int*   ei  = (const int*)d_in[1];
  const int*   bat = (const int*)d_in[2];
  const float* W1  = (const float*)d_in[3];  const float* bc1 = (const float*)d_in[4];
  const float* W2  = (const float*)d_in[5];  const float* bc2 = (const float*)d_in[6];
  const float* W3  = (const float*)d_in[7];  const float* bc3 = (const float*)d_in[8];
  const float* W4  = (const float*)d_in[9];  const float* bc4 = (const float*)d_in[10];
  const float* g1  = (const float*)d_in[11]; const float* bt1 = (const float*)d_in[12];
  const float* g2  = (const float*)d_in[13]; const float* bt2 = (const float*)d_in[14];
  const float* g3  = (const float*)d_in[15]; const float* bt3 = (const float*)d_in[16];

  const int N = in_sizes[0] / 3;
  const int E = in_sizes[1] / 2;
  const int* src = ei;
  const int* dst = ei + E;
  const size_t Epad = (size_t)E + (size_t)(ROWPAD - 1) * N + 64;

  float* base = (float*)d_ws;
  size_t o = 0;
  auto alloc = [&](size_t n) -> float* {
    float* p = base + o;
    o += (n + 63) & ~(size_t)63;
    return p;
  };
  // zeroed region (contiguous from d_ws start):
  float* psum   = alloc(64 * 32);
  float* pcnt   = alloc(64);
  unsigned* pmax = (unsigned*)alloc(64 * 32);
  float* bnacc  = alloc(3 * 128);  // per-layer [sum64][sumsq64]
  size_t zero_elems = o;
  // 0xFF region:
  unsigned* pmin = (unsigned*)alloc(64 * 32);
  // uninitialized (fully overwritten before read):
  int2*  erec  = (int2*)alloc(2 * Epad);
  float* dinv  = alloc(N);
  int*   hist  = (int*)alloc(N);
  int*   offs  = (int*)alloc(N + 1);
  int*   bsum  = (int*)alloc(256);
  int*   bbase = (int*)alloc(257);
  int*   bcnt  = (int*)alloc(MAXB);
  int*   bbase2 = (int*)alloc(MAXB + 1);
  int*   bcur  = (int*)alloc(MAXB);
  float* ab    = alloc(128);
  float* bias2 = alloc(192);          // L2[64] L3[64] L4[32]
  u16*   wt2   = (u16*)alloc(8192);   // bf16 [4][64][64]
  u16*   wt3   = (u16*)alloc(8192);
  u16*   wt4   = (u16*)alloc(4096);   // bf16 [4][32][64]
  float* t1f   = alloc(3 * (size_t)N);
  float* t2f   = alloc(3 * (size_t)N);
  float* t3f   = alloc(3 * (size_t)N);
  u16*   T0    = (u16*)alloc((size_t)N * 32);  // bf16 [N][64]
  u16*   T1    = (u16*)alloc((size_t)N * 32);
  u16*   T2    = (u16*)alloc((size_t)N * 32);
  u16*   T3    = (u16*)alloc((size_t)N * 32);
  float* C32   = alloc((size_t)N * 32);

  hipMemsetAsync(d_ws, 0, zero_elems * sizeof(float), stream);
  hipMemsetAsync(pmin, 0xFF, 64 * 32 * sizeof(unsigned), stream);

  const int NB = (N + 255) / 256;
  const int SB = (N + SC_CHUNK - 1) / SC_CHUNK;
  const int S  = (N + HSEG - 1) / HSEG;
  const int SP = S * HSEG;
  const int NBK = (N + 255) >> 8;
  unsigned* partial = (unsigned*)T0;  // alias
  int2* ebuck = (int2*)T2;            // alias

  k_wprep<<<64, 256, 0, stream>>>(W2, W3, W4, wt2, wt3, wt4);
  k_histseg<<<dim3(S, HC, 2), 256, 0, stream>>>(src, dst, partial, E, SP);
  k_histred<<<NB, 256, 0, stream>>>((const u8*)partial, dinv, hist, N, SP);
  k_scan1<<<SB, 256, 0, stream>>>(hist, bsum, N);
  k_scan2<<<1, 256, 0, stream>>>(bsum, bbase, SB);
  k_scan3<<<SB, 256, 0, stream>>>(hist, bbase, offs, N, SB);
  k_bcnt<<<NBK, 256, 0, stream>>>(hist, bcnt, N);
  k_bscan<<<1, 256, 0, stream>>>(bcnt, bbase2, bcur, NBK);
  k_part<<<512, 256, 0, stream>>>(src, dst, bcur, ebuck, E);
  k_place<<<NBK, 256, 0, stream>>>(ebuck, bbase2, offs, dinv, erec, N);

  const int PB64 = (N * 64 + 255) / 256;
  const int TB = (N + 63) / 64;
  const v4i* erec4 = (const v4i*)erec;

  // ---- layer 1: Fin=3 -> 64 (f32 props, merged combine -> bf16 T0) ----
  k_prop3<<<NB, 256, 0, stream>>>(x, nullptr, t1f, offs, erec4, N, 0);
  k_prop3<<<NB, 256, 0, stream>>>(t1f, x, t2f, offs, erec4, N, 1);
  k_prop3<<<NB, 256, 0, stream>>>(t2f, t1f, t3f, offs, erec4, N, 1);
  k_combine1<<<(N + 3) / 4, 256, 0, stream>>>(T0, x, t1f, t2f, t3f, W1, bc1, N);
  k_bnstats<<<BN_GRID, 256, 0, stream>>>(T0, bnacc, N);
  k_bnfinal3<<<1, 64, 0, stream>>>(bnacc, g1, bt1, W2, bc2, ab, bias2, 1.0f / N, 64);

  // ---- layer 2 ----
  k_prop64b<<<PB64, 256, 0, stream>>>(T0, ab, nullptr, nullptr, T1, offs, erec4, N, 0);
  k_prop64b<<<PB64, 256, 0, stream>>>(T1, nullptr, T0, ab, T2, offs, erec4, N, 1);
  k_prop64b<<<PB64, 256, 0, stream>>>(T2, nullptr, T1, nullptr, T3, offs, erec4, N, 1);
  k_combine_m<64, true, true><<<TB, 256, 0, stream>>>(T0, T0, T1, T2, T3, wt2, ab, bias2,
                                                      bnacc + 128, N);
  k_bnfinal3<<<1, 64, 0, stream>>>(bnacc + 128, g2, bt2, W3, bc3, ab, bias2 + 64, 1.0f / N, 64);

  // ---- layer 3 ----
  k_prop64b<<<PB64, 256, 0, stream>>>(T0, ab, nullptr, nullptr, T1, offs, erec4, N, 0);
  k_prop64b<<<PB64, 256, 0, stream>>>(T1, nullptr, T0, ab, T2, offs, erec4, N, 1);
  k_prop64b<<<PB64, 256, 0, stream>>>(T2, nullptr, T1, nullptr, T3, offs, erec4, N, 1);
  k_combine_m<64, true, true><<<TB, 256, 0, stream>>>(T0, T0, T1, T2, T3, wt3, ab, bias2 + 64,
                                                      bnacc + 256, N);
  k_bnfinal3<<<1, 64, 0, stream>>>(bnacc + 256, g3, bt3, W4, bc4, ab, bias2 + 128, 1.0f / N, 32);

  // ---- layer 4: 64 -> 32 (f32 out C32) ----
  k_prop64b<<<PB64, 256, 0, stream>>>(T0, ab, nullptr, nullptr, T1, offs, erec4, N, 0);
  k_prop64b<<<PB64, 256, 0, stream>>>(T1, nullptr, T0, ab, T2, offs, erec4, N, 1);
  k_prop64b<<<PB64, 256, 0, stream>>>(T2, nullptr, T1, nullptr, T3, offs, erec4, N, 1);
  k_combine_m<32, false, false><<<TB, 256, 0, stream>>>(C32, T0, T1, T2, T3, wt4, ab, bias2 + 128,
                                                        nullptr, N);

  // ---- pool (L2-normalize fused) ----
  k_pool2<<<(N + POOL_CHUNK - 1) / POOL_CHUNK, 256, 0, stream>>>(C32, bat, psum, pmax, pmin, pcnt, N);
  k_poolfin<<<64, 32, 0, stream>>>(psum, pmax, pmin, pcnt, (float*)d_out);
}